// Round 4
// baseline (87.813 us; speedup 1.0000x reference)
//
#include <hip/hip_runtime.h>

#define BB 4
#define NN 4096
#define DD 128
#define RB 8            // rows per block (2 per wave)

// Kernel 1: per-row projections. One wave per row; lane l covers dims l, l+64.
// SoA outputs: si[row] = x·a1;  e1[row] = exp(sj), e2[row] = exp(0.2*sj).
__global__ __launch_bounds__(256) void score_kernel(const float* __restrict__ x,
                                                    const float* __restrict__ a,
                                                    float* __restrict__ si,
                                                    float* __restrict__ e1,
                                                    float* __restrict__ e2) {
    int wave = threadIdx.x >> 6;
    int lane = threadIdx.x & 63;
    int row  = blockIdx.x * 4 + wave;   // grid covers B*N rows exactly
    const float* xr = x + (size_t)row * DD;
    float x0 = xr[lane];
    float x1 = xr[lane + 64];
    float d1 = x0 * a[lane]      + x1 * a[lane + 64];
    float d2 = x0 * a[DD + lane] + x1 * a[DD + lane + 64];
    #pragma unroll
    for (int off = 1; off < 64; off <<= 1) {
        d1 += __shfl_xor(d1, off, 64);
        d2 += __shfl_xor(d2, off, 64);
    }
    if (lane == 0) {
        si[row] = d1;
        e1[row] = __expf(d2);
        e2[row] = __expf(0.2f * d2);
    }
}

// Kernel 2: one block per RB rows. E1/E2 planes staged SoA in LDS (32 KB).
// Hot loop per element: p = max(A1*E1j, A2*E2j)  — exact identity since
// leaky(t)=max(t,0.2t) and exp is monotone. 2 mul + 1 max, zero TRANS,
// zero branches. VGPR ~50 -> LDS-limited 5 blocks/CU (20 waves).
__global__ __launch_bounds__(256) void softmax_kernel(const float* __restrict__ si_g,
                                                      const float* __restrict__ e1_g,
                                                      const float* __restrict__ e2_g,
                                                      float* __restrict__ out) {
    __shared__ float s_e1[NN];    // 16 KB
    __shared__ float s_e2[NN];    // 16 KB
    __shared__ float red[4];

    const int b    = blockIdx.x >> 9;          // 512 blocks per batch
    const int i0   = (blockIdx.x & 511) * RB;
    const int tid  = threadIdx.x;
    const int wave = tid >> 6;
    const int lane = tid & 63;

    // Stage both planes; track max(E1) while loading (mj = log(Emax), only
    // needs to be approximate: m cancels in normalization).
    const float* e1b = e1_g + b * NN;
    const float* e2b = e2_g + b * NN;
    float lmax = 0.f;
    #pragma unroll
    for (int k = 0; k < 4; ++k) {
        const int idx = k * 1024 + tid * 4;
        float4 v1 = *reinterpret_cast<const float4*>(e1b + idx);
        float4 v2 = *reinterpret_cast<const float4*>(e2b + idx);
        *reinterpret_cast<float4*>(s_e1 + idx) = v1;
        *reinterpret_cast<float4*>(s_e2 + idx) = v2;
        lmax = fmaxf(fmaxf(fmaxf(v1.x, v1.y), fmaxf(v1.z, v1.w)), lmax);
    }
    #pragma unroll
    for (int off = 1; off < 64; off <<= 1)
        lmax = fmaxf(lmax, __shfl_xor(lmax, off, 64));
    if (lane == 0) red[wave] = lmax;
    __syncthreads();
    const float Emax = fmaxf(fmaxf(red[0], red[1]), fmaxf(red[2], red[3]));
    const float mj = __logf(Emax);

    #pragma unroll
    for (int r = 0; r < RB / 4; ++r) {
        const int i = i0 + wave * (RB / 4) + r;
        const float sival = si_g[b * NN + i];
        const float c = sival + mj;
        const float m = fmaxf(c, 0.2f * c);            // leaky(si+mj): row max
        const float A1 = __expf(sival - m);
        const float A2 = __expf(0.2f * sival - m);

        float lsum = 0.f;
        #pragma unroll
        for (int g = 0; g < 16; ++g) {
            const int j = g * 256 + lane * 4;
            float4 v1 = *reinterpret_cast<const float4*>(s_e1 + j);
            float4 v2 = *reinterpret_cast<const float4*>(s_e2 + j);
            lsum += fmaxf(A1 * v1.x, A2 * v2.x) + fmaxf(A1 * v1.y, A2 * v2.y)
                  + fmaxf(A1 * v1.z, A2 * v2.z) + fmaxf(A1 * v1.w, A2 * v2.w);
        }
        #pragma unroll
        for (int off = 1; off < 64; off <<= 1)
            lsum += __shfl_xor(lsum, off, 64);
        const float inv = 1.f / lsum;
        const float B1 = A1 * inv;
        const float B2 = A2 * inv;

        float* orow = out + (size_t)(b * NN + i) * NN;
        #pragma unroll
        for (int g = 0; g < 16; ++g) {
            const int j = g * 256 + lane * 4;
            float4 v1 = *reinterpret_cast<const float4*>(s_e1 + j);
            float4 v2 = *reinterpret_cast<const float4*>(s_e2 + j);
            float4 v = make_float4(fmaxf(B1 * v1.x, B2 * v2.x),
                                   fmaxf(B1 * v1.y, B2 * v2.y),
                                   fmaxf(B1 * v1.z, B2 * v2.z),
                                   fmaxf(B1 * v1.w, B2 * v2.w));
            *reinterpret_cast<float4*>(orow + j) = v;
        }
    }
}

extern "C" void kernel_launch(void* const* d_in, const int* in_sizes, int n_in,
                              void* d_out, int out_size, void* d_ws, size_t ws_size,
                              hipStream_t stream) {
    const float* x = (const float*)d_in[0];
    const float* a = (const float*)d_in[1];
    float* out = (float*)d_out;
    float* si = (float*)d_ws;                 // B*N floats
    float* e1 = si + BB * NN;                 // B*N floats
    float* e2 = e1 + BB * NN;                 // B*N floats (192 KB total)

    score_kernel<<<(BB * NN) / 4, 256, 0, stream>>>(x, a, si, e1, e2);
    softmax_kernel<<<(BB * NN) / RB, 256, 0, stream>>>(si, e1, e2, out);
}

// Round 5
// 63.652 us; speedup vs baseline: 1.3796x; 1.3796x over previous
//
#include <hip/hip_runtime.h>

#define BB 4
#define NN 4096
#define DD 128
#define RB 8

typedef float vf4 __attribute__((ext_vector_type(4)));

__device__ __forceinline__ float ex2(float x) { return __builtin_amdgcn_exp2f(x); }

// K1: per-row projections in log2 domain. One wave per row.
// si_lg[r] = (x[r]·a1)·log2e ; sj_lg[r] = (x[r]·a2)·log2e
__global__ __launch_bounds__(256) void score_kernel(const float* __restrict__ x,
                                                    const float* __restrict__ a,
                                                    float* __restrict__ si_lg,
                                                    float* __restrict__ sj_lg) {
    const float L2E = 1.4426950408889634f;
    int wave = threadIdx.x >> 6;
    int lane = threadIdx.x & 63;
    int row  = blockIdx.x * 4 + wave;
    const float* xr = x + (size_t)row * DD;
    float x0 = xr[lane];
    float x1 = xr[lane + 64];
    float d1 = x0 * a[lane]      + x1 * a[lane + 64];
    float d2 = x0 * a[DD + lane] + x1 * a[DD + lane + 64];
    #pragma unroll
    for (int off = 1; off < 64; off <<= 1) {
        d1 += __shfl_xor(d1, off, 64);
        d2 += __shfl_xor(d2, off, 64);
    }
    if (lane == 0) {
        si_lg[row] = d1 * L2E;
        sj_lg[row] = d2 * L2E;
    }
}

// K_denom: per-row log-denominators. 1024 blocks x 4 waves; each wave holds the
// batch's E1=exp2(sj~), E2=exp2(0.2*sj~) in 128 VGPRs (no stores to hide, so
// low occupancy is fine) and computes 4 rows:
//   mr = leaky(si~ + max_j sj~)   (row max in log2 domain; leaky monotone)
//   denom = sum_j max(A1*E1j, A2*E2j),  A1=exp2(si~-mr), A2=exp2(0.2si~-mr)
//   M[i] = mr + log2(denom)
// Every product term <= 1, factors <= exp2(69): no overflow. denom in [1,4096].
__global__ __launch_bounds__(256) void denom_kernel(const float* __restrict__ si_lg,
                                                    const float* __restrict__ sj_lg,
                                                    float* __restrict__ Mrow) {
    int wave_g = blockIdx.x * 4 + (threadIdx.x >> 6);   // 0..4095
    int lane   = threadIdx.x & 63;
    int b      = wave_g >> 10;                          // 1024 waves per batch
    int i0     = (wave_g & 1023) * 4;                   // 4 rows per wave

    const float* sjb = sj_lg + b * NN;
    vf4 e1[16], e2[16];
    float kmax = -INFINITY;
    #pragma unroll
    for (int g = 0; g < 16; ++g) {
        vf4 s = *reinterpret_cast<const vf4*>(sjb + g * 256 + lane * 4);
        kmax = fmaxf(fmaxf(fmaxf(s.x, s.y), fmaxf(s.z, s.w)), kmax);
        e2[g].x = ex2(0.2f * s.x); e2[g].y = ex2(0.2f * s.y);
        e2[g].z = ex2(0.2f * s.z); e2[g].w = ex2(0.2f * s.w);
        e1[g].x = ex2(s.x); e1[g].y = ex2(s.y);
        e1[g].z = ex2(s.z); e1[g].w = ex2(s.w);
    }
    #pragma unroll
    for (int off = 1; off < 64; off <<= 1)
        kmax = fmaxf(kmax, __shfl_xor(kmax, off, 64));

    #pragma unroll
    for (int r = 0; r < 4; ++r) {
        const int i = i0 + r;
        const float si = si_lg[b * NN + i];
        const float t  = si + kmax;
        const float mr = fmaxf(t, 0.2f * t);
        const float A1 = ex2(si - mr);
        const float A2 = ex2(0.2f * si - mr);
        float sum = 0.f;
        #pragma unroll
        for (int g = 0; g < 16; ++g) {
            sum += fmaxf(A1 * e1[g].x, A2 * e2[g].x)
                 + fmaxf(A1 * e1[g].y, A2 * e2[g].y)
                 + fmaxf(A1 * e1[g].z, A2 * e2[g].z)
                 + fmaxf(A1 * e1[g].w, A2 * e2[g].w);
        }
        #pragma unroll
        for (int off = 1; off < 64; off <<= 1)
            sum += __shfl_xor(sum, off, 64);
        if (lane == 0)
            Mrow[b * NN + i] = mr + __builtin_amdgcn_logf(sum);
    }
}

// K2: single-pass streamer. Per block: 8 rows; sj~ plane in 64 VGPRs (R2's
// proven footprint). Per element: add + fma + max + exp2 -> store. No LDS,
// no barriers, no reductions.
//   out = exp2( max(si~+sj~, 0.2*(si~+sj~)) - M[i] )
__global__ __launch_bounds__(256) void stream_kernel(const float* __restrict__ si_lg,
                                                     const float* __restrict__ sj_lg,
                                                     const float* __restrict__ Mrow,
                                                     float* __restrict__ out) {
    const int b    = blockIdx.x >> 9;           // 512 blocks per batch
    const int i0   = (blockIdx.x & 511) * RB;
    const int wave = threadIdx.x >> 6;
    const int lane = threadIdx.x & 63;

    const float* sjb = sj_lg + b * NN;
    vf4 sv[16];
    #pragma unroll
    for (int g = 0; g < 16; ++g)
        sv[g] = *reinterpret_cast<const vf4*>(sjb + g * 256 + lane * 4);

    #pragma unroll
    for (int r = 0; r < RB / 4; ++r) {
        const int i = i0 + wave * (RB / 4) + r;
        const float si = si_lg[b * NN + i];
        const float M  = Mrow[b * NN + i];
        const float u  = si - M;                 // + sj~          (pos branch)
        const float v  = 0.2f * si - M;          // + 0.2*sj~      (neg branch)

        float* orow = out + (size_t)(b * NN + i) * NN;
        #pragma unroll
        for (int g = 0; g < 16; ++g) {
            vf4 s = sv[g];
            vf4 o;
            o.x = ex2(fmaxf(u + s.x, fmaf(0.2f, s.x, v)));
            o.y = ex2(fmaxf(u + s.y, fmaf(0.2f, s.y, v)));
            o.z = ex2(fmaxf(u + s.z, fmaf(0.2f, s.z, v)));
            o.w = ex2(fmaxf(u + s.w, fmaf(0.2f, s.w, v)));
            *reinterpret_cast<vf4*>(orow + g * 256 + lane * 4) = o;
        }
    }
}

extern "C" void kernel_launch(void* const* d_in, const int* in_sizes, int n_in,
                              void* d_out, int out_size, void* d_ws, size_t ws_size,
                              hipStream_t stream) {
    const float* x = (const float*)d_in[0];
    const float* a = (const float*)d_in[1];
    float* out = (float*)d_out;
    float* si_lg = (float*)d_ws;                 // B*N floats
    float* sj_lg = si_lg + BB * NN;              // B*N floats
    float* Mrow  = sj_lg + BB * NN;              // B*N floats (192 KB total)

    score_kernel<<<(BB * NN) / 4, 256, 0, stream>>>(x, a, si_lg, sj_lg);
    denom_kernel<<<1024, 256, 0, stream>>>(si_lg, sj_lg, Mrow);
    stream_kernel<<<(BB * NN) / RB, 256, 0, stream>>>(si_lg, sj_lg, Mrow, out);
}

// Round 6
// 56.728 us; speedup vs baseline: 1.5480x; 1.1221x over previous
//
#include <hip/hip_runtime.h>

#define BB 4
#define NN 4096
#define DD 128
#define RB 8

typedef float vf4 __attribute__((ext_vector_type(4)));

__device__ __forceinline__ float ex2(float x) { return __builtin_amdgcn_exp2f(x); }

// K1: per-row projections in log2 domain. One wave per row.
// si_lg[r] = (x[r]·a1)·log2e ; sj_lg[r] = (x[r]·a2)·log2e
__global__ __launch_bounds__(256) void score_kernel(const float* __restrict__ x,
                                                    const float* __restrict__ a,
                                                    float* __restrict__ si_lg,
                                                    float* __restrict__ sj_lg) {
    const float L2E = 1.4426950408889634f;
    int wave = threadIdx.x >> 6;
    int lane = threadIdx.x & 63;
    int row  = blockIdx.x * 4 + wave;
    const float* xr = x + (size_t)row * DD;
    float x0 = xr[lane];
    float x1 = xr[lane + 64];
    float d1 = x0 * a[lane]      + x1 * a[lane + 64];
    float d2 = x0 * a[DD + lane] + x1 * a[DD + lane + 64];
    #pragma unroll
    for (int off = 1; off < 64; off <<= 1) {
        d1 += __shfl_xor(d1, off, 64);
        d2 += __shfl_xor(d2, off, 64);
    }
    if (lane == 0) {
        si_lg[row] = d1 * L2E;
        sj_lg[row] = d2 * L2E;
    }
}

// K2: R2's proven structure (batch s_j plane in 64 VGPRs/lane, two passes,
// 2 rows per wave) with:
//  - exp2-domain algebra: z = max(u+s, 0.2s+v) (leaky via fmax), exp2 only
//  - row max via pure wave reduce (each wave holds ALL 4096 elements):
//    no LDS, no barriers
//  - write-pass normalization folded into exponent: out = exp2(z - log2(sum))
//  - nontemporal float4 stores (output is written once, never re-read)
__global__ __launch_bounds__(256) void softmax_kernel(const float* __restrict__ si_lg,
                                                      const float* __restrict__ sj_lg,
                                                      float* __restrict__ out) {
    const int b    = blockIdx.x >> 9;           // 512 blocks per batch
    const int i0   = (blockIdx.x & 511) * RB;
    const int wave = threadIdx.x >> 6;
    const int lane = threadIdx.x & 63;

    // Load entire batch plane: lane holds j = g*256 + lane*4 .. +3 (64 elems).
    const float* sjb = sj_lg + b * NN;
    vf4 sv[16];
    float kmax = -INFINITY;
    #pragma unroll
    for (int g = 0; g < 16; ++g) {
        vf4 s = *reinterpret_cast<const vf4*>(sjb + g * 256 + lane * 4);
        sv[g] = s;
        kmax = fmaxf(fmaxf(fmaxf(s.x, s.y), fmaxf(s.z, s.w)), kmax);
    }
    #pragma unroll
    for (int off = 1; off < 64; off <<= 1)
        kmax = fmaxf(kmax, __shfl_xor(kmax, off, 64));   // covers all of j

    #pragma unroll
    for (int r = 0; r < RB / 4; ++r) {
        const int i = i0 + wave * (RB / 4) + r;
        const float si = si_lg[b * NN + i];
        const float c  = si + kmax;
        const float m  = fmaxf(c, 0.2f * c);    // row max in log2 units
        const float u  = si - m;                 // z = max(u+s, 0.2s+v) <= 0
        const float v  = 0.2f * si - m;

        float lsum = 0.f;
        #pragma unroll
        for (int g = 0; g < 16; ++g) {
            vf4 s = sv[g];
            lsum += ex2(fmaxf(u + s.x, fmaf(0.2f, s.x, v)))
                  + ex2(fmaxf(u + s.y, fmaf(0.2f, s.y, v)))
                  + ex2(fmaxf(u + s.z, fmaf(0.2f, s.z, v)))
                  + ex2(fmaxf(u + s.w, fmaf(0.2f, s.w, v)));
        }
        #pragma unroll
        for (int off = 1; off < 64; off <<= 1)
            lsum += __shfl_xor(lsum, off, 64);
        const float L  = __builtin_amdgcn_logf(lsum);   // log2; denom in [1,4096]
        const float u2 = u - L;
        const float v2 = v - L;

        float* orow = out + (size_t)(b * NN + i) * NN;
        #pragma unroll
        for (int g = 0; g < 16; ++g) {
            vf4 s = sv[g];
            vf4 o;
            o.x = ex2(fmaxf(u2 + s.x, fmaf(0.2f, s.x, v2)));
            o.y = ex2(fmaxf(u2 + s.y, fmaf(0.2f, s.y, v2)));
            o.z = ex2(fmaxf(u2 + s.z, fmaf(0.2f, s.z, v2)));
            o.w = ex2(fmaxf(u2 + s.w, fmaf(0.2f, s.w, v2)));
            __builtin_nontemporal_store(o, reinterpret_cast<vf4*>(orow + g * 256 + lane * 4));
        }
    }
}

extern "C" void kernel_launch(void* const* d_in, const int* in_sizes, int n_in,
                              void* d_out, int out_size, void* d_ws, size_t ws_size,
                              hipStream_t stream) {
    const float* x = (const float*)d_in[0];
    const float* a = (const float*)d_in[1];
    float* out = (float*)d_out;
    float* si_lg = (float*)d_ws;                 // B*N floats
    float* sj_lg = si_lg + BB * NN;              // B*N floats (128 KB, << ws)

    score_kernel<<<(BB * NN) / 4, 256, 0, stream>>>(x, a, si_lg, sj_lg);
    softmax_kernel<<<(BB * NN) / RB, 256, 0, stream>>>(si_lg, sj_lg, out);
}

// Round 7
// 52.276 us; speedup vs baseline: 1.6798x; 1.0852x over previous
//
#include <hip/hip_runtime.h>

#define BB 4
#define NN 4096
#define DD 128
#define RB 8

typedef float vf4 __attribute__((ext_vector_type(4)));

__device__ __forceinline__ float ex2(float x) { return __builtin_amdgcn_exp2f(x); }

// K1: per-row projections in log2 domain. One wave per row.
// si_lg[r] = (x[r]·a1)·log2e ; sj_lg[r] = (x[r]·a2)·log2e
__global__ __launch_bounds__(256) void score_kernel(const float* __restrict__ x,
                                                    const float* __restrict__ a,
                                                    float* __restrict__ si_lg,
                                                    float* __restrict__ sj_lg) {
    const float L2E = 1.4426950408889634f;
    int wave = threadIdx.x >> 6;
    int lane = threadIdx.x & 63;
    int row  = blockIdx.x * 4 + wave;
    const float* xr = x + (size_t)row * DD;
    float x0 = xr[lane];
    float x1 = xr[lane + 64];
    float d1 = x0 * a[lane]      + x1 * a[lane + 64];
    float d2 = x0 * a[DD + lane] + x1 * a[DD + lane + 64];
    #pragma unroll
    for (int off = 1; off < 64; off <<= 1) {
        d1 += __shfl_xor(d1, off, 64);
        d2 += __shfl_xor(d2, off, 64);
    }
    if (lane == 0) {
        si_lg[row] = d1 * L2E;
        sj_lg[row] = d2 * L2E;
    }
}

// K2: R2's proven structure (batch s_j plane in 64 VGPRs/lane, two passes,
// 2 rows per wave, no LDS, no barriers) + exp2-domain algebra:
//   z = max(u + s, 0.2*s + v)   (leaky-relu via fmax, exact identity)
//   out = exp2(z - log2(sum))   (normalization folded into the exponent)
// Plain (temporal) float4 stores — NT measured -4 us in R6.
__global__ __launch_bounds__(256) void softmax_kernel(const float* __restrict__ si_lg,
                                                      const float* __restrict__ sj_lg,
                                                      float* __restrict__ out) {
    const int b    = blockIdx.x >> 9;           // 512 blocks per batch
    const int i0   = (blockIdx.x & 511) * RB;
    const int wave = threadIdx.x >> 6;
    const int lane = threadIdx.x & 63;

    // Load entire batch plane: lane holds j = g*256 + lane*4 .. +3 (64 elems).
    const float* sjb = sj_lg + b * NN;
    vf4 sv[16];
    float kmax = -INFINITY;
    #pragma unroll
    for (int g = 0; g < 16; ++g) {
        vf4 s = *reinterpret_cast<const vf4*>(sjb + g * 256 + lane * 4);
        sv[g] = s;
        kmax = fmaxf(fmaxf(fmaxf(s.x, s.y), fmaxf(s.z, s.w)), kmax);
    }
    #pragma unroll
    for (int off = 1; off < 64; off <<= 1)
        kmax = fmaxf(kmax, __shfl_xor(kmax, off, 64));   // covers all of j

    #pragma unroll
    for (int r = 0; r < RB / 4; ++r) {
        const int i = i0 + wave * (RB / 4) + r;
        const float si = si_lg[b * NN + i];
        const float c  = si + kmax;
        const float m  = fmaxf(c, 0.2f * c);     // row max in log2 units
        const float u  = si - m;
        const float v  = 0.2f * si - m;

        float lsum = 0.f;
        #pragma unroll
        for (int g = 0; g < 16; ++g) {
            vf4 s = sv[g];
            lsum += ex2(fmaxf(u + s.x, fmaf(0.2f, s.x, v)))
                  + ex2(fmaxf(u + s.y, fmaf(0.2f, s.y, v)))
                  + ex2(fmaxf(u + s.z, fmaf(0.2f, s.z, v)))
                  + ex2(fmaxf(u + s.w, fmaf(0.2f, s.w, v)));
        }
        #pragma unroll
        for (int off = 1; off < 64; off <<= 1)
            lsum += __shfl_xor(lsum, off, 64);
        const float L  = __builtin_amdgcn_logf(lsum);   // log2(denom), denom in [1,4096]
        const float u2 = u - L;
        const float v2 = v - L;

        float* orow = out + (size_t)(b * NN + i) * NN;
        #pragma unroll
        for (int g = 0; g < 16; ++g) {
            vf4 s = sv[g];
            vf4 o;
            o.x = ex2(fmaxf(u2 + s.x, fmaf(0.2f, s.x, v2)));
            o.y = ex2(fmaxf(u2 + s.y, fmaf(0.2f, s.y, v2)));
            o.z = ex2(fmaxf(u2 + s.z, fmaf(0.2f, s.z, v2)));
            o.w = ex2(fmaxf(u2 + s.w, fmaf(0.2f, s.w, v2)));
            *reinterpret_cast<vf4*>(orow + g * 256 + lane * 4) = o;
        }
    }
}

extern "C" void kernel_launch(void* const* d_in, const int* in_sizes, int n_in,
                              void* d_out, int out_size, void* d_ws, size_t ws_size,
                              hipStream_t stream) {
    const float* x = (const float*)d_in[0];
    const float* a = (const float*)d_in[1];
    float* out = (float*)d_out;
    float* si_lg = (float*)d_ws;                 // B*N floats
    float* sj_lg = si_lg + BB * NN;              // B*N floats (128 KB, << ws)

    score_kernel<<<(BB * NN) / 4, 256, 0, stream>>>(x, a, si_lg, sj_lg);
    softmax_kernel<<<(BB * NN) / RB, 256, 0, stream>>>(si_lg, sj_lg, out);
}